// Round 1
// baseline (993.864 us; speedup 1.0000x reference)
//
#include <hip/hip_runtime.h>
#include <math.h>

#define EMB 768
#define NH 12
#define HD 64
#define NL 12
#define NV 50257
#define MAXS 1024
#define S_PAST 1023
#define E3 2304
#define E4 3072

// workspace float offsets
#define WS_H    0
#define WS_QKV  768
#define WS_ATTN 3072
#define WS_FC   3840
#define WS_PART 6912
#define WS_HF   13248

__device__ __forceinline__ void blockReduce2(float& a, float& b, volatile float* ra, volatile float* rb) {
  int lane = threadIdx.x & 63, wid = threadIdx.x >> 6;
#pragma unroll
  for (int o = 32; o > 0; o >>= 1) { a += __shfl_down(a, o); b += __shfl_down(b, o); }
  if (lane == 0) { ra[wid] = a; rb[wid] = b; }
  __syncthreads();
  if (threadIdx.x == 0) {
    ra[0] = ra[0] + ra[1] + ra[2] + ra[3];
    rb[0] = rb[0] + rb[1] + rb[2] + rb[3];
  }
  __syncthreads();
  a = ra[0]; b = rb[0];
}

// bulk copy of past_key/past_value into the output regions (slot S overwritten later)
__global__ void copy_kv(const float* __restrict__ pk, const float* __restrict__ pv,
                        float* __restrict__ opk, float* __restrict__ opv, long n) {
  long i = (long)blockIdx.x * blockDim.x + threadIdx.x;
  long stride = (long)gridDim.x * blockDim.x;
  for (; i < n; i += stride) { opk[i] = pk[i]; opv[i] = pv[i]; }
}

// h = wte[id] + wpe[S]; seed qkv with attn_b[layer 0]
__global__ void embed_kernel(const int* __restrict__ ids, const float* __restrict__ wte,
                             const float* __restrict__ wpe, const float* __restrict__ attn_b,
                             float* __restrict__ hvec, float* __restrict__ qkv) {
  int idx = blockIdx.x * 256 + threadIdx.x;
  if (idx < E3) qkv[idx] = attn_b[idx];
  if (idx < EMB) {
    int id = ids[0];
    hvec[idx] = wte[(size_t)id * EMB + idx] + wpe[(size_t)S_PAST * EMB + idx];
  }
}

// out[j] += sum_e LN(h)[e] * W[l][e][j]   (split-K over blockIdx.y, 96 e per block)
__global__ void ln_gemv(const float* __restrict__ hvec, const float* __restrict__ g,
                        const float* __restrict__ bb, const float* __restrict__ W,
                        float* __restrict__ out, int N, int l) {
  __shared__ float lh[EMB];
  __shared__ float xs[96];
  __shared__ float ra[4], rb[4];
  int tid = threadIdx.x;
  float s1 = 0.f, s2 = 0.f;
  for (int e = tid; e < EMB; e += 256) { float v = hvec[e]; lh[e] = v; s1 += v; s2 += v * v; }
  blockReduce2(s1, s2, ra, rb);
  float mean = s1 * (1.f / EMB);
  float var = s2 * (1.f / EMB) - mean * mean;
  float rstd = rsqrtf(var + 1e-5f);
  int e0 = blockIdx.y * 96;
  if (tid < 96) {
    int e = e0 + tid;
    xs[tid] = (lh[e] - mean) * rstd * g[l * EMB + e] + bb[l * EMB + e];
  }
  __syncthreads();
  int j = blockIdx.x * 256 + tid;
  const float* Wp = W + (size_t)l * EMB * N + (size_t)e0 * N + j;
  float acc = 0.f;
#pragma unroll 8
  for (int i = 0; i < 96; i++) acc += xs[i] * Wp[(size_t)i * N];
  atomicAdd(&out[j], acc);
}

// flash-style attention partials: one block per (head, 128-key chunk)
__global__ void attn_partial(const float* __restrict__ qkv, const float* __restrict__ pk,
                             const float* __restrict__ pv, const float* __restrict__ mask,
                             const float* __restrict__ fc_b, float* __restrict__ fcout,
                             float* __restrict__ part, int l) {
  int h = blockIdx.x >> 3;
  int c = blockIdx.x & 7;
  int tid = threadIdx.x, lane = tid & 63, wid = tid >> 6;
  __shared__ float qs[64];
  __shared__ float sc[128];
  __shared__ float ored[4][64];
  if (tid < 64) qs[tid] = qkv[h * 64 + tid];
  if (blockIdx.x < 12) fcout[blockIdx.x * 256 + tid] = fc_b[l * E4 + blockIdx.x * 256 + tid];
  __syncthreads();
  int t0 = c * 128;
  const float* Kb = pk + ((size_t)(l * NH + h) * MAXS) * HD;
  for (int i = 0; i < 32; i++) {
    int t = t0 + wid * 32 + i;
    float kv = (t == S_PAST) ? qkv[EMB + h * 64 + lane] : Kb[(size_t)t * HD + lane];
    float p = qs[lane] * kv;
#pragma unroll
    for (int o = 32; o > 0; o >>= 1) p += __shfl_down(p, o);
    if (lane == 0) sc[wid * 32 + i] = p * 0.125f + (1.f - mask[t]) * (-1e9f);
  }
  __syncthreads();
  if (wid == 0) {
    float a = sc[lane], b2 = sc[lane + 64];
    float m = fmaxf(a, b2);
#pragma unroll
    for (int o = 32; o > 0; o >>= 1) m = fmaxf(m, __shfl_down(m, o));
    m = __shfl(m, 0);
    float ea = expf(a - m), eb = expf(b2 - m);
    sc[lane] = ea; sc[lane + 64] = eb;
    float s = ea + eb;
#pragma unroll
    for (int o = 32; o > 0; o >>= 1) s += __shfl_down(s, o);
    if (lane == 0) { part[(h * 8 + c) * 66 + 0] = m; part[(h * 8 + c) * 66 + 1] = s; }
  }
  __syncthreads();
  const float* Vb = pv + ((size_t)(l * NH + h) * MAXS) * HD;
  float acc = 0.f;
  for (int i = 0; i < 32; i++) {
    int t = t0 + wid * 32 + i;
    float vv = (t == S_PAST) ? qkv[2 * EMB + h * 64 + lane] : Vb[(size_t)t * HD + lane];
    acc += sc[wid * 32 + i] * vv;
  }
  ored[wid][lane] = acc;
  __syncthreads();
  if (tid < 64) {
    float o4 = ored[0][tid] + ored[1][tid] + ored[2][tid] + ored[3][tid];
    part[(h * 8 + c) * 66 + 2 + tid] = o4;
  }
}

// combine 8 chunk-partials per head; also write the new K/V slot into outputs
__global__ void attn_combine(const float* __restrict__ part, const float* __restrict__ qkv,
                             float* __restrict__ attn_out, float* __restrict__ opk,
                             float* __restrict__ opv, int l) {
  int h = blockIdx.x, d = threadIdx.x; // 64 threads
  float M = -1e30f;
  for (int c = 0; c < 8; c++) M = fmaxf(M, part[(h * 8 + c) * 66]);
  float T = 0.f, o = 0.f;
  for (int c = 0; c < 8; c++) {
    float w = expf(part[(h * 8 + c) * 66] - M);
    T += part[(h * 8 + c) * 66 + 1] * w;
    o += part[(h * 8 + c) * 66 + 2 + d] * w;
  }
  attn_out[h * 64 + d] = o / T;
  size_t slot = (((size_t)(l * NH + h)) * MAXS + S_PAST) * HD + d;
  opk[slot] = qkv[EMB + h * 64 + d];
  opv[slot] = qkv[2 * EMB + h * 64 + d];
}

// h[j] += sum_e a[e] * proj_w[l][e][j] (+bias once)
__global__ void proj_gemv(const float* __restrict__ a, const float* __restrict__ W,
                          const float* __restrict__ bias, float* __restrict__ hout, int l) {
  __shared__ float xs[96];
  int tid = threadIdx.x;
  int e0 = blockIdx.y * 96;
  if (tid < 96) xs[tid] = a[e0 + tid];
  __syncthreads();
  int j = blockIdx.x * 256 + tid;
  const float* Wp = W + (size_t)l * EMB * EMB + (size_t)e0 * EMB + j;
  float acc = (blockIdx.y == 0) ? bias[l * EMB + j] : 0.f;
#pragma unroll 8
  for (int i = 0; i < 96; i++) acc += xs[i] * Wp[(size_t)i * EMB];
  atomicAdd(&hout[j], acc);
}

// h[j] += sum_e gelu(fc[e]) * mlp_w[l][e][j] (+bias once); seed next layer's qkv
__global__ void mlp_gemv(const float* __restrict__ fcv, const float* __restrict__ W,
                         const float* __restrict__ bias, const float* __restrict__ attn_b,
                         float* __restrict__ hout, float* __restrict__ qkv, int l) {
  __shared__ float xs[192];
  int tid = threadIdx.x;
  int e0 = blockIdx.y * 192;
  if (tid < 192) {
    float x = fcv[e0 + tid];
    xs[tid] = 0.5f * x * (1.f + tanhf(0.7978845608028654f * (x + 0.044715f * x * x * x)));
  }
  __syncthreads();
  int j = blockIdx.x * 256 + tid;
  const float* Wp = W + (size_t)l * E4 * EMB + (size_t)e0 * EMB + j;
  float acc = (blockIdx.y == 0) ? bias[l * EMB + j] : 0.f;
#pragma unroll 8
  for (int i = 0; i < 192; i++) acc += xs[i] * Wp[(size_t)i * EMB];
  atomicAdd(&hout[j], acc);
  int bid = blockIdx.y * 3 + blockIdx.x;
  if (l + 1 < NL && bid < 9) qkv[bid * 256 + tid] = attn_b[(l + 1) * E3 + bid * 256 + tid];
}

__global__ void lnf_kernel(const float* __restrict__ hvec, const float* __restrict__ g,
                           const float* __restrict__ b, float* __restrict__ hf) {
  __shared__ float ra[4], rb[4];
  int tid = threadIdx.x;
  float s1 = 0.f, s2 = 0.f;
  float v0[3];
  int k = 0;
  for (int e = tid; e < EMB; e += 256, k++) { float v = hvec[e]; v0[k] = v; s1 += v; s2 += v * v; }
  blockReduce2(s1, s2, ra, rb);
  float mean = s1 * (1.f / EMB);
  float var = s2 * (1.f / EMB) - mean * mean;
  float rstd = rsqrtf(var + 1e-5f);
  k = 0;
  for (int e = tid; e < EMB; e += 256, k++) hf[e] = (v0[k] - mean) * rstd * g[e] + b[e];
}

// logits[v] = dot(hf, wte[v]); one wave per row
__global__ void logits_kernel(const float* __restrict__ hf, const float* __restrict__ wte,
                              float* __restrict__ out) {
  __shared__ float4 hfs[192];
  int tid = threadIdx.x, lane = tid & 63, wid = tid >> 6;
  if (tid < 192) hfs[tid] = ((const float4*)hf)[tid];
  __syncthreads();
  int v = blockIdx.x * 4 + wid;
  if (v >= NV) return;
  const float4* row = (const float4*)(wte + (size_t)v * EMB);
  float acc = 0.f;
#pragma unroll
  for (int i = 0; i < 3; i++) {
    float4 a = row[lane + 64 * i], b = hfs[lane + 64 * i];
    acc += a.x * b.x + a.y * b.y + a.z * b.z + a.w * b.w;
  }
#pragma unroll
  for (int o = 32; o > 0; o >>= 1) acc += __shfl_down(acc, o);
  if (lane == 0) out[v] = acc;
}

extern "C" void kernel_launch(void* const* d_in, const int* in_sizes, int n_in,
                              void* d_out, int out_size, void* d_ws, size_t ws_size,
                              hipStream_t stream) {
  const int* input_ids = (const int*)d_in[0];
  const float* past_key = (const float*)d_in[1];
  const float* past_value = (const float*)d_in[2];
  const float* mask = (const float*)d_in[4];
  const float* wte = (const float*)d_in[5];
  const float* wpe = (const float*)d_in[6];
  const float* ln1_g = (const float*)d_in[7];
  const float* ln1_b = (const float*)d_in[8];
  const float* attn_w = (const float*)d_in[9];
  const float* attn_b = (const float*)d_in[10];
  const float* proj_w = (const float*)d_in[11];
  const float* proj_b = (const float*)d_in[12];
  const float* ln2_g = (const float*)d_in[13];
  const float* ln2_b = (const float*)d_in[14];
  const float* fc_w = (const float*)d_in[15];
  const float* fc_b = (const float*)d_in[16];
  const float* mlp_w = (const float*)d_in[17];
  const float* mlp_b = (const float*)d_in[18];
  const float* lnf_g = (const float*)d_in[19];
  const float* lnf_b = (const float*)d_in[20];

  float* out = (float*)d_out;
  float* out_logits = out;
  float* out_pk = out + NV;
  float* out_pv = out_pk + (size_t)NL * NH * MAXS * HD;

  float* ws = (float*)d_ws;
  float* wh = ws + WS_H;
  float* wqkv = ws + WS_QKV;
  float* wattn = ws + WS_ATTN;
  float* wfc = ws + WS_FC;
  float* wpart = ws + WS_PART;
  float* whf = ws + WS_HF;

  long nkv = (long)NL * NH * MAXS * HD;
  copy_kv<<<2048, 256, 0, stream>>>(past_key, past_value, out_pk, out_pv, nkv);
  embed_kernel<<<9, 256, 0, stream>>>(input_ids, wte, wpe, attn_b, wh, wqkv);

  for (int l = 0; l < NL; l++) {
    ln_gemv<<<dim3(9, 8), 256, 0, stream>>>(wh, ln1_g, ln1_b, attn_w, wqkv, E3, l);
    attn_partial<<<96, 256, 0, stream>>>(wqkv, past_key, past_value, mask, fc_b, wfc, wpart, l);
    attn_combine<<<12, 64, 0, stream>>>(wpart, wqkv, wattn, out_pk, out_pv, l);
    proj_gemv<<<dim3(3, 8), 256, 0, stream>>>(wattn, proj_w, proj_b, wh, l);
    ln_gemv<<<dim3(12, 8), 256, 0, stream>>>(wh, ln2_g, ln2_b, fc_w, wfc, E4, l);
    mlp_gemv<<<dim3(3, 16), 256, 0, stream>>>(wfc, mlp_w, mlp_b, attn_b, wh, wqkv, l);
  }
  lnf_kernel<<<1, 256, 0, stream>>>(wh, lnf_g, lnf_b, whf);
  logits_kernel<<<(NV + 3) / 4, 256, 0, stream>>>(whf, wte, out_logits);
}

// Round 2
// 494.293 us; speedup vs baseline: 2.0107x; 2.0107x over previous
//
#include <hip/hip_runtime.h>
#include <math.h>

#define EMB 768
#define NH 12
#define HD 64
#define NL 12
#define NV 50257
#define MAXS 1024
#define S_PAST 1023
#define E3 2304
#define E4 3072

// workspace float offsets
#define WS_H    0
#define WS_QKV  768
#define WS_FC   3072
#define WS_PART 6144   // 96 entries * 68 floats

__device__ __forceinline__ void blockReduce2(float& a, float& b, volatile float* ra, volatile float* rb) {
  int lane = threadIdx.x & 63, wid = threadIdx.x >> 6;
#pragma unroll
  for (int o = 32; o > 0; o >>= 1) { a += __shfl_down(a, o); b += __shfl_down(b, o); }
  if (lane == 0) { ra[wid] = a; rb[wid] = b; }
  __syncthreads();
  if (threadIdx.x == 0) {
    ra[0] = ra[0] + ra[1] + ra[2] + ra[3];
    rb[0] = rb[0] + rb[1] + rb[2] + rb[3];
  }
  __syncthreads();
  a = ra[0]; b = rb[0];
}

// h = wte[id] + wpe[S]; seed qkv with attn_b[layer 0]
__global__ void embed_kernel(const int* __restrict__ ids, const float* __restrict__ wte,
                             const float* __restrict__ wpe, const float* __restrict__ attn_b,
                             float* __restrict__ hvec, float* __restrict__ qkv) {
  int idx = blockIdx.x * 256 + threadIdx.x;
  if (idx < E3) qkv[idx] = attn_b[idx];
  if (idx < EMB) {
    int id = ids[0];
    hvec[idx] = wte[(size_t)id * EMB + idx] + wpe[(size_t)S_PAST * EMB + idx];
  }
}

// out[j] += sum_e LN(h)[e] * W[l][e][j]; float4 over j, 64 rows per block (blockIdx.y)
__global__ void ln_gemv4(const float* __restrict__ hvec, const float* __restrict__ g,
                         const float* __restrict__ bb, const float* __restrict__ W,
                         float* __restrict__ out, int N, int l) {
  __shared__ float lh[EMB];
  __shared__ float xs[64];
  __shared__ float ra[4], rb[4];
  __shared__ float4 red[4][64];
  int tid = threadIdx.x, lane = tid & 63, wid = tid >> 6;
  float s1 = 0.f, s2 = 0.f;
  for (int e = tid; e < EMB; e += 256) { float v = hvec[e]; lh[e] = v; s1 += v; s2 += v * v; }
  blockReduce2(s1, s2, ra, rb);
  float mean = s1 * (1.f / EMB);
  float var = s2 * (1.f / EMB) - mean * mean;
  float rstd = rsqrtf(var + 1e-5f);
  int e0 = blockIdx.y * 64;
  if (tid < 64) {
    int e = e0 + tid;
    xs[tid] = (lh[e] - mean) * rstd * g[l * EMB + e] + bb[l * EMB + e];
  }
  __syncthreads();
  int j4 = blockIdx.x * 64 + lane;
  int N4 = N >> 2;
  const float4* W4 = (const float4*)(W + (size_t)l * EMB * N) + (size_t)e0 * N4 + j4;
  float4 acc = {0.f, 0.f, 0.f, 0.f};
#pragma unroll
  for (int i = 0; i < 16; i++) {
    int r = wid + i * 4;
    float x = xs[r];
    float4 wv = W4[(size_t)r * N4];
    acc.x += x * wv.x; acc.y += x * wv.y; acc.z += x * wv.z; acc.w += x * wv.w;
  }
  red[wid][lane] = acc;
  __syncthreads();
  if (wid == 0) {
    float4 a0 = red[0][lane], a1 = red[1][lane], a2 = red[2][lane], a3 = red[3][lane];
    float rx = a0.x + a1.x + a2.x + a3.x;
    float ry = a0.y + a1.y + a2.y + a3.y;
    float rz = a0.z + a1.z + a2.z + a3.z;
    float rw = a0.w + a1.w + a2.w + a3.w;
    float* op = out + (size_t)j4 * 4;
    atomicAdd(op + 0, rx); atomicAdd(op + 1, ry);
    atomicAdd(op + 2, rz); atomicAdd(op + 3, rw);
  }
}

// attention partials for one (head, 128-key chunk); also copies K/V rows to outputs
__global__ void attn_kv(const float* __restrict__ qkv, const float* __restrict__ pk,
                        const float* __restrict__ pv, const float* __restrict__ mask,
                        float* __restrict__ opk, float* __restrict__ opv,
                        float* __restrict__ part, int l) {
  int h = blockIdx.x >> 3, c = blockIdx.x & 7;
  int tid = threadIdx.x, lane = tid & 63, wid = tid >> 6;
  int sub = tid & 15, grp = tid >> 4;
  __shared__ float4 qs4[16];
  __shared__ float sc[128];
  __shared__ float4 redo[4][16];
  if (tid < 16) qs4[tid] = ((const float4*)(qkv + h * 64))[tid];
  __syncthreads();
  size_t base = ((size_t)(l * NH + h) * MAXS) * HD;
  const float4* K4 = (const float4*)(pk + base);
  const float4* V4 = (const float4*)(pv + base);
  float4* oK4 = (float4*)(opk + base);
  float4* oV4 = (float4*)(opv + base);
  int t0 = c * 128;
#pragma unroll
  for (int i = 0; i < 8; i++) {
    int key = grp + i * 16;
    int t = t0 + key;
    float4 k4 = (t == S_PAST) ? ((const float4*)(qkv + EMB + h * 64))[sub] : K4[(size_t)t * 16 + sub];
    oK4[(size_t)t * 16 + sub] = k4;
    float4 q4 = qs4[sub];
    float p = q4.x * k4.x + q4.y * k4.y + q4.z * k4.z + q4.w * k4.w;
    p += __shfl_xor(p, 1); p += __shfl_xor(p, 2);
    p += __shfl_xor(p, 4); p += __shfl_xor(p, 8);
    if (sub == 0) sc[key] = p * 0.125f + (1.f - mask[t]) * (-1e9f);
  }
  __syncthreads();
  if (wid == 0) {
    float a = sc[lane], b2 = sc[lane + 64];
    float m = fmaxf(a, b2);
#pragma unroll
    for (int o = 32; o > 0; o >>= 1) m = fmaxf(m, __shfl_down(m, o));
    m = __shfl(m, 0);
    float ea = expf(a - m), eb = expf(b2 - m);
    sc[lane] = ea; sc[lane + 64] = eb;
    float s = ea + eb;
#pragma unroll
    for (int o = 32; o > 0; o >>= 1) s += __shfl_down(s, o);
    if (lane == 0) { part[(h * 8 + c) * 68 + 0] = m; part[(h * 8 + c) * 68 + 1] = s; }
  }
  __syncthreads();
  float4 acc = {0.f, 0.f, 0.f, 0.f};
#pragma unroll
  for (int i = 0; i < 8; i++) {
    int key = grp + i * 16;
    int t = t0 + key;
    float4 v4 = (t == S_PAST) ? ((const float4*)(qkv + 2 * EMB + h * 64))[sub] : V4[(size_t)t * 16 + sub];
    oV4[(size_t)t * 16 + sub] = v4;
    float w = sc[key];
    acc.x += w * v4.x; acc.y += w * v4.y; acc.z += w * v4.z; acc.w += w * v4.w;
  }
  acc.x += __shfl_xor(acc.x, 16); acc.y += __shfl_xor(acc.y, 16);
  acc.z += __shfl_xor(acc.z, 16); acc.w += __shfl_xor(acc.w, 16);
  acc.x += __shfl_xor(acc.x, 32); acc.y += __shfl_xor(acc.y, 32);
  acc.z += __shfl_xor(acc.z, 32); acc.w += __shfl_xor(acc.w, 32);
  if (lane < 16) redo[wid][lane] = acc;
  __syncthreads();
  if (tid < 16) {
    float4 a0 = redo[0][tid], a1 = redo[1][tid], a2 = redo[2][tid], a3 = redo[3][tid];
    float4 r;
    r.x = a0.x + a1.x + a2.x + a3.x;
    r.y = a0.y + a1.y + a2.y + a3.y;
    r.z = a0.z + a1.z + a2.z + a3.z;
    r.w = a0.w + a1.w + a2.w + a3.w;
    ((float4*)(part + (h * 8 + c) * 68 + 4))[tid] = r;
  }
}

// combine 8 chunk-partials for head h, then h += attn_out(head) @ proj_w[rows of head]
__global__ void proj_attn(const float* __restrict__ part, const float* __restrict__ W,
                          const float* __restrict__ bias, const float* __restrict__ fc_b,
                          float* __restrict__ hout, float* __restrict__ wfc, int l) {
  int jb = blockIdx.x;   // 0..2
  int h = blockIdx.y;    // 0..11
  int tid = threadIdx.x, lane = tid & 63, wid = tid >> 6;
  __shared__ float xs[64];
  __shared__ float4 red[4][64];
  if (tid < 64) {
    float M = -1e30f;
    for (int cc = 0; cc < 8; cc++) M = fmaxf(M, part[(h * 8 + cc) * 68]);
    float T = 0.f, o = 0.f;
    for (int cc = 0; cc < 8; cc++) {
      float w = expf(part[(h * 8 + cc) * 68] - M);
      T += part[(h * 8 + cc) * 68 + 1] * w;
      o += part[(h * 8 + cc) * 68 + 4 + tid] * w;
    }
    xs[tid] = o / T;
  }
  int bid = h * 3 + jb;
  if (bid < 12) wfc[bid * 256 + tid] = fc_b[l * E4 + bid * 256 + tid];
  __syncthreads();
  int j4 = jb * 64 + lane;
  const int N4 = EMB >> 2;
  const float4* W4 = (const float4*)(W + (size_t)l * EMB * EMB) + (size_t)(h * 64) * N4 + j4;
  float4 acc = {0.f, 0.f, 0.f, 0.f};
#pragma unroll
  for (int i = 0; i < 16; i++) {
    int r = wid + i * 4;
    float x = xs[r];
    float4 wv = W4[(size_t)r * N4];
    acc.x += x * wv.x; acc.y += x * wv.y; acc.z += x * wv.z; acc.w += x * wv.w;
  }
  red[wid][lane] = acc;
  __syncthreads();
  if (wid == 0) {
    float4 a0 = red[0][lane], a1 = red[1][lane], a2 = red[2][lane], a3 = red[3][lane];
    float rx = a0.x + a1.x + a2.x + a3.x;
    float ry = a0.y + a1.y + a2.y + a3.y;
    float rz = a0.z + a1.z + a2.z + a3.z;
    float rw = a0.w + a1.w + a2.w + a3.w;
    if (h == 0) {
      const float* bp = bias + l * EMB + j4 * 4;
      rx += bp[0]; ry += bp[1]; rz += bp[2]; rw += bp[3];
    }
    float* op = hout + (size_t)j4 * 4;
    atomicAdd(op + 0, rx); atomicAdd(op + 1, ry);
    atomicAdd(op + 2, rz); atomicAdd(op + 3, rw);
  }
}

// h[j] += sum_e gelu(fc[e]) * mlp_w[l][e][j]; 128 rows per block; seed next qkv
__global__ void mlp_gemv4(const float* __restrict__ fcv, const float* __restrict__ W,
                          const float* __restrict__ bias, const float* __restrict__ attn_b,
                          float* __restrict__ hout, float* __restrict__ qkv, int l) {
  __shared__ float xs[128];
  __shared__ float4 red[4][64];
  int tid = threadIdx.x, lane = tid & 63, wid = tid >> 6;
  int e0 = blockIdx.y * 128;
  if (tid < 128) {
    float x = fcv[e0 + tid];
    xs[tid] = 0.5f * x * (1.f + tanhf(0.7978845608028654f * (x + 0.044715f * x * x * x)));
  }
  int bid = blockIdx.y * 3 + blockIdx.x;
  if (l + 1 < NL && bid < 9) qkv[bid * 256 + tid] = attn_b[(l + 1) * E3 + bid * 256 + tid];
  __syncthreads();
  int j4 = blockIdx.x * 64 + lane;
  const int N4 = EMB >> 2;
  const float4* W4 = (const float4*)(W + (size_t)l * E4 * EMB) + (size_t)e0 * N4 + j4;
  float4 acc = {0.f, 0.f, 0.f, 0.f};
#pragma unroll
  for (int i = 0; i < 32; i++) {
    int r = wid + i * 4;
    float x = xs[r];
    float4 wv = W4[(size_t)r * N4];
    acc.x += x * wv.x; acc.y += x * wv.y; acc.z += x * wv.z; acc.w += x * wv.w;
  }
  red[wid][lane] = acc;
  __syncthreads();
  if (wid == 0) {
    float4 a0 = red[0][lane], a1 = red[1][lane], a2 = red[2][lane], a3 = red[3][lane];
    float rx = a0.x + a1.x + a2.x + a3.x;
    float ry = a0.y + a1.y + a2.y + a3.y;
    float rz = a0.z + a1.z + a2.z + a3.z;
    float rw = a0.w + a1.w + a2.w + a3.w;
    if (blockIdx.y == 0) {
      const float* bp = bias + l * EMB + j4 * 4;
      rx += bp[0]; ry += bp[1]; rz += bp[2]; rw += bp[3];
    }
    float* op = hout + (size_t)j4 * 4;
    atomicAdd(op + 0, rx); atomicAdd(op + 1, ry);
    atomicAdd(op + 2, rz); atomicAdd(op + 3, rw);
  }
}

// final LN fused into logits: logits[v] = dot(LN(h), wte[v]); one wave per row
__global__ void logits_lnf(const float* __restrict__ hvec, const float* __restrict__ g,
                           const float* __restrict__ b, const float* __restrict__ wte,
                           float* __restrict__ out) {
  __shared__ float4 xs4[192];
  __shared__ float ra[4], rb[4];
  int tid = threadIdx.x, lane = tid & 63, wid = tid >> 6;
  float s1 = 0.f, s2 = 0.f;
  float v0[3];
  int k = 0;
  for (int e = tid; e < EMB; e += 256, k++) { float v = hvec[e]; v0[k] = v; s1 += v; s2 += v * v; }
  blockReduce2(s1, s2, ra, rb);
  float mean = s1 * (1.f / EMB);
  float var = s2 * (1.f / EMB) - mean * mean;
  float rstd = rsqrtf(var + 1e-5f);
  k = 0;
  for (int e = tid; e < EMB; e += 256, k++)
    ((float*)xs4)[e] = (v0[k] - mean) * rstd * g[e] + b[e];
  __syncthreads();
  int v = blockIdx.x * 4 + wid;
  if (v >= NV) return;
  const float4* row = (const float4*)(wte + (size_t)v * EMB);
  float acc = 0.f;
#pragma unroll
  for (int i = 0; i < 3; i++) {
    float4 a = row[lane + 64 * i], x = xs4[lane + 64 * i];
    acc += a.x * x.x + a.y * x.y + a.z * x.z + a.w * x.w;
  }
#pragma unroll
  for (int o = 32; o > 0; o >>= 1) acc += __shfl_down(acc, o);
  if (lane == 0) out[v] = acc;
}

extern "C" void kernel_launch(void* const* d_in, const int* in_sizes, int n_in,
                              void* d_out, int out_size, void* d_ws, size_t ws_size,
                              hipStream_t stream) {
  const int* input_ids = (const int*)d_in[0];
  const float* past_key = (const float*)d_in[1];
  const float* past_value = (const float*)d_in[2];
  const float* mask = (const float*)d_in[4];
  const float* wte = (const float*)d_in[5];
  const float* wpe = (const float*)d_in[6];
  const float* ln1_g = (const float*)d_in[7];
  const float* ln1_b = (const float*)d_in[8];
  const float* attn_w = (const float*)d_in[9];
  const float* attn_b = (const float*)d_in[10];
  const float* proj_w = (const float*)d_in[11];
  const float* proj_b = (const float*)d_in[12];
  const float* ln2_g = (const float*)d_in[13];
  const float* ln2_b = (const float*)d_in[14];
  const float* fc_w = (const float*)d_in[15];
  const float* fc_b = (const float*)d_in[16];
  const float* mlp_w = (const float*)d_in[17];
  const float* mlp_b = (const float*)d_in[18];
  const float* lnf_g = (const float*)d_in[19];
  const float* lnf_b = (const float*)d_in[20];

  float* out = (float*)d_out;
  float* out_logits = out;
  float* out_pk = out + NV;
  float* out_pv = out_pk + (size_t)NL * NH * MAXS * HD;

  float* ws = (float*)d_ws;
  float* wh = ws + WS_H;
  float* wqkv = ws + WS_QKV;
  float* wfc = ws + WS_FC;
  float* wpart = ws + WS_PART;

  embed_kernel<<<9, 256, 0, stream>>>(input_ids, wte, wpe, attn_b, wh, wqkv);

  for (int l = 0; l < NL; l++) {
    ln_gemv4<<<dim3(9, 12), 256, 0, stream>>>(wh, ln1_g, ln1_b, attn_w, wqkv, E3, l);
    attn_kv<<<96, 256, 0, stream>>>(wqkv, past_key, past_value, mask, out_pk, out_pv, wpart, l);
    proj_attn<<<dim3(3, 12), 256, 0, stream>>>(wpart, proj_w, proj_b, fc_b, wh, wfc, l);
    ln_gemv4<<<dim3(12, 12), 256, 0, stream>>>(wh, ln2_g, ln2_b, fc_w, wfc, E4, l);
    mlp_gemv4<<<dim3(3, 24), 256, 0, stream>>>(wfc, mlp_w, mlp_b, attn_b, wh, wqkv, l);
  }
  logits_lnf<<<12565, 256, 0, stream>>>(wh, lnf_g, lnf_b, wte, out_logits);
}